// Round 1
// baseline (627.851 us; speedup 1.0000x reference)
//
#include <hip/hip_runtime.h>

// TinyNeRF fused-MLP inference, fp16 MFMA (16x16x32), fp32 accumulate.
//
// ws layout:
//   fp16 weights, pre-transposed W^T[F_pad][K_pad], zero-padded:
//     W1t [128][64]  @ half 0      (g1: K 36->64)
//     W2t [128][128] @ 8192
//     W3t [128][128] @ 24576
//     W4t [128][128] @ 40960
//     DWt [16][128]  @ 57344      (d: F 1->16)
//     FWt [128][128] @ 59392
//     C1t [64][160]  @ 75776      (c1: K 152->160)
//     C2t [16][64]   @ 86016      (c2: F 3->16)
//   fp32 biases (padded) @ byte 174080: b1[128] b2[128] b3[128] b4[128]
//     bd[16] bf[128] bc1[64] bc2[16]  (736 floats)
//
// Main kernel: block=256 (4 waves), each wave independently processes 32
// points: encode -> g1..g4 -> {density, feature} -> c1 -> c2, activations in
// a per-wave LDS tile [32][192] fp16 with 16B-chunk XOR swizzle (^ p&7).
// MFMA in transposed orientation (A=W^T rows=out-dims, B=X cols=points) so
// C-frags pack into ds_write_b64. No inter-wave deps; single barrier.

typedef _Float16 half8 __attribute__((ext_vector_type(8)));
typedef _Float16 half4v __attribute__((ext_vector_type(4)));
typedef float f32x4 __attribute__((ext_vector_type(4)));

#define MFMA16(A, B, C) __builtin_amdgcn_mfma_f32_16x16x32_f16(A, B, C, 0, 0, 0)

#define WH_TOTAL 87040
#define WB_BYTE_OFF (WH_TOTAL * 2)
#define WB_TOTAL 736

__device__ __forceinline__ float softplus_f(float x) {
  return fmaxf(x, 0.f) + log1pf(expf(-fabsf(x)));
}
__device__ __forceinline__ float sigmoid_f(float x) {
  return 1.f / (1.f + expf(-x));
}

// swizzled LDS address: row stride 192 halves (24 16B chunks), chunk ^= p&7
__device__ __forceinline__ _Float16* lptr(_Float16* L, int p, int col) {
  int chunk = col >> 3, sub = col & 7;
  return L + p * 192 + (((chunk ^ (p & 7)) << 3) | sub);
}

template <int KS>
__device__ __forceinline__ void load_bf(_Float16* L, int lane, half8 (&bf)[2][KS]) {
  const int g = lane >> 4, lr = lane & 15;
#pragma unroll
  for (int pt = 0; pt < 2; ++pt)
#pragma unroll
    for (int ks = 0; ks < KS; ++ks)
      bf[pt][ks] = *(const half8*)lptr(L, pt * 16 + lr, ks * 32 + g * 8);
}

// generic layer: OT output 16-tiles, KS k-steps, optional relu, writes LDS
template <int OT, int KS, bool RELU>
__device__ __forceinline__ void layer_store(_Float16* L, int lane,
                                            const _Float16* __restrict__ Wt,
                                            const float* __restrict__ bias,
                                            const half8 (&bf)[2][KS]) {
  const int g = lane >> 4, lr = lane & 15;
#pragma unroll
  for (int og = 0; og < OT; og += 4) {
    f32x4 acc[4][2];
#pragma unroll
    for (int o4 = 0; o4 < 4; ++o4) {
      f32x4 bv = *(const f32x4*)(bias + (og + o4) * 16 + g * 4);
      acc[o4][0] = bv;
      acc[o4][1] = bv;
    }
#pragma unroll
    for (int ks = 0; ks < KS; ++ks) {
#pragma unroll
      for (int o4 = 0; o4 < 4; ++o4) {
        half8 af = *(const half8*)(Wt + ((og + o4) * 16 + lr) * (KS * 32) + ks * 32 + g * 8);
        acc[o4][0] = MFMA16(af, bf[0][ks], acc[o4][0]);
        acc[o4][1] = MFMA16(af, bf[1][ks], acc[o4][1]);
      }
    }
#pragma unroll
    for (int o4 = 0; o4 < 4; ++o4)
#pragma unroll
      for (int pt = 0; pt < 2; ++pt) {
        half4v h;
#pragma unroll
        for (int j = 0; j < 4; ++j) {
          float v = acc[o4][pt][j];
          if (RELU) v = fmaxf(v, 0.f);
          h[j] = (_Float16)v;
        }
        *(half4v*)lptr(L, pt * 16 + lr, (og + o4) * 16 + g * 4) = h;
      }
  }
}

__global__ void prep_kernel(const float* __restrict__ g1w, const float* __restrict__ g2w,
                            const float* __restrict__ g3w, const float* __restrict__ g4w,
                            const float* __restrict__ dw, const float* __restrict__ fw,
                            const float* __restrict__ c1w, const float* __restrict__ c2w,
                            const float* __restrict__ g1b, const float* __restrict__ g2b,
                            const float* __restrict__ g3b, const float* __restrict__ g4b,
                            const float* __restrict__ db, const float* __restrict__ fb,
                            const float* __restrict__ c1b, const float* __restrict__ c2b,
                            _Float16* __restrict__ wh, float* __restrict__ wb) {
  int i = blockIdx.x * 256 + threadIdx.x;
  if (i < WH_TOTAL) {
    const float* W;
    int base, Fr, Kr, Kp;
    if (i < 8192)       { base = 0;     W = g1w; Fr = 128; Kr = 36;  Kp = 64; }
    else if (i < 24576) { base = 8192;  W = g2w; Fr = 128; Kr = 128; Kp = 128; }
    else if (i < 40960) { base = 24576; W = g3w; Fr = 128; Kr = 128; Kp = 128; }
    else if (i < 57344) { base = 40960; W = g4w; Fr = 128; Kr = 128; Kp = 128; }
    else if (i < 59392) { base = 57344; W = dw;  Fr = 1;   Kr = 128; Kp = 128; }
    else if (i < 75776) { base = 59392; W = fw;  Fr = 128; Kr = 128; Kp = 128; }
    else if (i < 86016) { base = 75776; W = c1w; Fr = 64;  Kr = 152; Kp = 160; }
    else                { base = 86016; W = c2w; Fr = 3;   Kr = 64;  Kp = 64; }
    int r = i - base, o = r / Kp, k = r % Kp;
    float v = (k < Kr && o < Fr) ? W[k * Fr + o] : 0.f;
    wh[i] = (_Float16)v;
  } else if (i < WH_TOTAL + WB_TOTAL) {
    int j = i - WH_TOTAL;
    float v = 0.f;
    if (j < 128) v = g1b[j];
    else if (j < 256) v = g2b[j - 128];
    else if (j < 384) v = g3b[j - 256];
    else if (j < 512) v = g4b[j - 384];
    else if (j < 528) { int t = j - 512; v = (t < 1) ? db[t] : 0.f; }
    else if (j < 656) v = fb[j - 528];
    else if (j < 720) v = c1b[j - 656];
    else { int t = j - 720; v = (t < 3) ? c2b[t] : 0.f; }
    wb[j] = v;
  }
}

__global__ __launch_bounds__(256, 3) void nerf_fused(
    const float* __restrict__ pos, const float* __restrict__ dirs,
    const _Float16* __restrict__ wh, const float* __restrict__ wb,
    float* __restrict__ out, int n) {
  __shared__ _Float16 lds[4][32 * 192];  // 48 KB
  const int wave = threadIdx.x >> 6, lane = threadIdx.x & 63;
  const int g = lane >> 4, lr = lane & 15;
  const int pbase = blockIdx.x * 128 + wave * 32;
  _Float16* L = lds[wave];

  // ---- positional encode: 2 threads per point (even: pos, odd: dir) ----
  {
    int p = lane >> 1;
    int gp = pbase + p;
    if ((lane & 1) == 0) {
      const float* xp = pos + gp * 3;
#pragma unroll
      for (int d = 0; d < 3; ++d) {
        float s, c;
        sincosf(xp[d] * 3.14159265358979f, &s, &c);
#pragma unroll
        for (int l = 0; l < 6; ++l) {
          *lptr(L, p, d * 12 + l) = (_Float16)s;
          *lptr(L, p, d * 12 + 6 + l) = (_Float16)c;
          float s2 = 2.f * s * c, c2 = c * c - s * s;  // double-angle
          s = s2; c = c2;
        }
      }
#pragma unroll
      for (int col = 36; col < 64; ++col) *lptr(L, p, col) = (_Float16)0.f;
    } else {
      const float* xd = dirs + gp * 3;
#pragma unroll
      for (int d = 0; d < 3; ++d) {
        float s, c;
        sincosf(xd[d] * 3.14159265358979f, &s, &c);
#pragma unroll
        for (int l = 0; l < 4; ++l) {
          *lptr(L, p, 128 + d * 8 + l) = (_Float16)s;
          *lptr(L, p, 128 + d * 8 + 4 + l) = (_Float16)c;
          float s2 = 2.f * s * c, c2 = c * c - s * s;
          s = s2; c = c2;
        }
      }
#pragma unroll
      for (int col = 152; col < 160; ++col) *lptr(L, p, col) = (_Float16)0.f;
    }
  }
  __syncthreads();

  // g1: K=64(padded), g2..g4: K=128, relu
  { half8 bf[2][2]; load_bf<2>(L, lane, bf); layer_store<8, 2, true>(L, lane, wh + 0, wb + 0, bf); }
  { half8 bf[2][4]; load_bf<4>(L, lane, bf); layer_store<8, 4, true>(L, lane, wh + 8192, wb + 128, bf); }
  { half8 bf[2][4]; load_bf<4>(L, lane, bf); layer_store<8, 4, true>(L, lane, wh + 24576, wb + 256, bf); }
  { half8 bf[2][4]; load_bf<4>(L, lane, bf); layer_store<8, 4, true>(L, lane, wh + 40960, wb + 384, bf); }

  // density (softplus -> out[3n..4n)) + feature (no relu), shared B-frags
  {
    half8 bf[2][4];
    load_bf<4>(L, lane, bf);
    f32x4 bd = *(const f32x4*)(wb + 512 + g * 4);
    f32x4 a0 = bd, a1 = bd;
#pragma unroll
    for (int ks = 0; ks < 4; ++ks) {
      half8 af = *(const half8*)(wh + 57344 + lr * 128 + ks * 32 + g * 8);
      a0 = MFMA16(af, bf[0][ks], a0);
      a1 = MFMA16(af, bf[1][ks], a1);
    }
    if (g == 0) {  // o==0 row holds the real density
      out[3 * n + pbase + lr] = softplus_f(a0[0]);
      out[3 * n + pbase + 16 + lr] = softplus_f(a1[0]);
    }
    layer_store<8, 4, false>(L, lane, wh + 59392, wb + 528, bf);
  }

  // c1: K=160 (feature 0..127 + dir_enc 128..151 + pad), writes cols 0..63
  { half8 bf[2][5]; load_bf<5>(L, lane, bf); layer_store<4, 5, true>(L, lane, wh + 75776, wb + 656, bf); }

  // c2 -> rgb (sigmoid), rows 0..2 valid
  {
    half8 bf[2][2];
    load_bf<2>(L, lane, bf);
    f32x4 bc = *(const f32x4*)(wb + 720 + g * 4);
    f32x4 a0 = bc, a1 = bc;
#pragma unroll
    for (int ks = 0; ks < 2; ++ks) {
      half8 af = *(const half8*)(wh + 86016 + lr * 64 + ks * 32 + g * 8);
      a0 = MFMA16(af, bf[0][ks], a0);
      a1 = MFMA16(af, bf[1][ks], a1);
    }
    if (g == 0) {
      int p0 = pbase + lr, p1 = pbase + 16 + lr;
      out[p0 * 3 + 0] = sigmoid_f(a0[0]);
      out[p0 * 3 + 1] = sigmoid_f(a0[1]);
      out[p0 * 3 + 2] = sigmoid_f(a0[2]);
      out[p1 * 3 + 0] = sigmoid_f(a1[0]);
      out[p1 * 3 + 1] = sigmoid_f(a1[1]);
      out[p1 * 3 + 2] = sigmoid_f(a1[2]);
    }
  }
}

extern "C" void kernel_launch(void* const* d_in, const int* in_sizes, int n_in,
                              void* d_out, int out_size, void* d_ws, size_t ws_size,
                              hipStream_t stream) {
  const float* pos = (const float*)d_in[0];
  const float* dirs = (const float*)d_in[1];
  const float* g1w = (const float*)d_in[2];
  const float* g1b = (const float*)d_in[3];
  const float* g2w = (const float*)d_in[4];
  const float* g2b = (const float*)d_in[5];
  const float* g3w = (const float*)d_in[6];
  const float* g3b = (const float*)d_in[7];
  const float* g4w = (const float*)d_in[8];
  const float* g4b = (const float*)d_in[9];
  const float* dw = (const float*)d_in[10];
  const float* db = (const float*)d_in[11];
  const float* fw = (const float*)d_in[12];
  const float* fb = (const float*)d_in[13];
  const float* c1w = (const float*)d_in[14];
  const float* c1b = (const float*)d_in[15];
  const float* c2w = (const float*)d_in[16];
  const float* c2b = (const float*)d_in[17];

  int n = in_sizes[0] / 3;  // 1048576

  _Float16* wh = (_Float16*)d_ws;
  float* wb = (float*)((char*)d_ws + WB_BYTE_OFF);

  prep_kernel<<<(WH_TOTAL + WB_TOTAL + 255) / 256, 256, 0, stream>>>(
      g1w, g2w, g3w, g4w, dw, fw, c1w, c2w,
      g1b, g2b, g3b, g4b, db, fb, c1b, c2b, wh, wb);

  int blocks = n / 128;
  nerf_fused<<<blocks, 256, 0, stream>>>(pos, dirs, wh, wb, (float*)d_out, n);
}

// Round 2
// 187.049 us; speedup vs baseline: 3.3566x; 3.3566x over previous
//
#include <hip/hip_runtime.h>

// TinyNeRF fused MLP, fp16 MFMA 16x16x32, fp32 accum.
// Round-2 design:
//  - Weights pre-baked by prep kernel into a 176 KB fp16 image in d_ws:
//    13 chunks (og-halves of each layer), rows XOR-swizzled ((row&7)<<4 on bytes)
//    for conflict-free ds_read_b128, and each layer's K-axis PERMUTED by
//    pi(k) so that layer L's MFMA C-fragment register layout equals layer
//    L+1's B-fragment layout => inter-layer transition is pure in-register
//    relu+cvt+repack (no LDS round trip, no cross-lane ops).
//  - Main kernel: 256 thr (4 waves), 64 pts/wave (4 MFMA sub-tiles).
//    Chunks staged global->LDS via global_load_lds_dwordx4, double-buffered
//    2x24KB, one __syncthreads per chunk (2-phase pipeline).
//  - Encodings computed per-lane directly in B-fragment form.

typedef _Float16 half8 __attribute__((ext_vector_type(8)));
typedef _Float16 half2v __attribute__((ext_vector_type(2)));
typedef float f32x4 __attribute__((ext_vector_type(4)));

typedef __attribute__((address_space(1))) const unsigned int GU32;
typedef __attribute__((address_space(3))) unsigned int LU32;

#define MFMA16(A,B,C) __builtin_amdgcn_mfma_f32_16x16x32_f16(A,B,C,0,0,0)

// image chunk bases (in halves)
#define G1A 0
#define G1B 4096
#define G2A 8192
#define G2B 16384
#define G3A 24576
#define G3B 32768
#define G4A 40960
#define G4B 49152
#define DCH 57344
#define FAC 59392
#define FBC 67584
#define C1C 75776
#define C2C 88064
#define IMG_HALVES 90112

// K-axis permutation: B-slot (ks,g,jj) must hold output dim
// (2ks + jj>>2)*16 + g*4 + (jj&3) of the previous layer.
__device__ __forceinline__ int permk(int s){
  int ks = s >> 5, gg = (s >> 3) & 3, jj = s & 7;
  return (2*ks + (jj >> 2))*16 + gg*4 + (jj & 3);
}

__global__ void prep(const float* __restrict__ g1w, const float* __restrict__ g2w,
                     const float* __restrict__ g3w, const float* __restrict__ g4w,
                     const float* __restrict__ dw,  const float* __restrict__ fw,
                     const float* __restrict__ c1w, const float* __restrict__ c2w,
                     _Float16* __restrict__ img) {
  int i = blockIdx.x*256 + threadIdx.x;
  if (i >= IMG_HALVES) return;
  float v; int o_loc, s, krowb, cb;
  if (i < G2A) {                       // g1a / g1b : [64][64], identity k
    cb = (i < G1B) ? G1A : G1B; int obase = (i < G1B) ? 0 : 64;
    int r = i - cb; o_loc = r >> 6; s = r & 63; krowb = 128;
    v = (s < 36) ? g1w[s*128 + obase + o_loc] : 0.f;
  } else if (i < DCH) {                // g2a..g4b : [64][128], perm k
    int r = i - G2A; int ch = r >> 13;
    cb = G2A + ch*8192; int li = r & 8191;
    const float* W = (ch < 2) ? g2w : (ch < 4) ? g3w : g4w;
    int obase = (ch & 1)*64;
    o_loc = li >> 7; s = li & 127; krowb = 256;
    v = W[permk(s)*128 + obase + o_loc];
  } else if (i < FAC) {                // d : [16][128], perm k
    cb = DCH; int r = i - DCH; o_loc = r >> 7; s = r & 127; krowb = 256;
    v = (o_loc == 0) ? dw[permk(s)] : 0.f;
  } else if (i < C1C) {                // fa / fb : [64][128], perm k
    cb = (i < FBC) ? FAC : FBC; int obase = (i < FBC) ? 0 : 64;
    int r = i - cb; o_loc = r >> 7; s = r & 127; krowb = 256;
    v = fw[permk(s)*128 + obase + o_loc];
  } else if (i < C2C) {                // c1 : [64][192], perm k (<128), dir identity
    cb = C1C; int r = i - C1C; o_loc = r/192; s = r%192; krowb = 384;
    v = (s < 128) ? c1w[permk(s)*64 + o_loc]
      : (s < 152) ? c1w[s*64 + o_loc] : 0.f;
  } else {                             // c2 : [16][128], perm k (<64)
    cb = C2C; int r = i - C2C; o_loc = r >> 7; s = r & 127; krowb = 256;
    v = (s < 64 && o_loc < 3) ? c2w[permk(s)*3 + o_loc] : 0.f;
  }
  int byte_in = (o_loc*krowb + 2*s) ^ ((o_loc & 7) << 4);
  *(_Float16*)((char*)img + (size_t)cb*2 + byte_in) = (_Float16)v;
}

__device__ __forceinline__ half8 mk8(uint2 a, uint2 b){
  union { unsigned int u[4]; half8 h; } x;
  x.u[0]=a.x; x.u[1]=a.y; x.u[2]=b.x; x.u[3]=b.y; return x.h;
}
__device__ __forceinline__ half8 mkh8(float a,float b,float c,float d,
                                      float e,float f,float g,float h){
  half8 r; r[0]=(_Float16)a; r[1]=(_Float16)b; r[2]=(_Float16)c; r[3]=(_Float16)d;
  r[4]=(_Float16)e; r[5]=(_Float16)f; r[6]=(_Float16)g; r[7]=(_Float16)h; return r;
}
__device__ __forceinline__ uint2 pack4(float a0,float a1,float a2,float a3,bool relu){
  if (relu){ a0=fmaxf(a0,0.f); a1=fmaxf(a1,0.f); a2=fmaxf(a2,0.f); a3=fmaxf(a3,0.f); }
  union { _Float16 h[4]; uint2 u; } x;
  x.h[0]=(_Float16)a0; x.h[1]=(_Float16)a1; x.h[2]=(_Float16)a2; x.h[3]=(_Float16)a3;
  return x.u;
}

// one og-half chunk: O=64 (og 0..3), writes pk[PKB..PKB+3]
template<int KROWB, int KS, int PKB, bool RELU>
__device__ __forceinline__ void chunk64(const _Float16* __restrict__ buf, int lane,
                                        const float* __restrict__ bias,
                                        const half8 (&bf)[4][5], uint2 (&pk)[8][4]) {
  const int g = lane >> 4, n = lane & 15;
  const int swz = (lane & 7) << 4;
  const char* lb = (const char*)buf + n*KROWB;
#pragma unroll
  for (int og = 0; og < 4; ++og) {
    half8 wf[KS];
#pragma unroll
    for (int ks = 0; ks < KS; ++ks)
      wf[ks] = *(const half8*)(lb + og*16*KROWB + ((ks*64 + g*16) ^ swz));
    f32x4 bv = *(const f32x4*)(bias + og*16 + g*4);
    f32x4 acc[4];
#pragma unroll
    for (int st = 0; st < 4; ++st) acc[st] = bv;
#pragma unroll
    for (int ks = 0; ks < KS; ++ks)
#pragma unroll
      for (int st = 0; st < 4; ++st)
        acc[st] = MFMA16(wf[ks], bf[st][ks], acc[st]);
#pragma unroll
    for (int st = 0; st < 4; ++st)
      pk[PKB+og][st] = pack4(acc[st][0], acc[st][1], acc[st][2], acc[st][3], RELU);
  }
}

#define STAGE(BASE_HALF, BUFSEL, ROUNDS) do{ \
  const char* s_ = (const char*)img + (size_t)(BASE_HALF)*2 + tid*16; \
  char* d_ = (char*)(&wbuf[BUFSEL][0]) + wave*1024; \
  _Pragma("unroll") \
  for (int r_ = 0; r_ < (ROUNDS); ++r_) \
    __builtin_amdgcn_global_load_lds((GU32*)(s_ + (size_t)r_*4096), \
                                     (LU32*)(d_ + r_*4096), 16, 0, 0); \
}while(0)

#define REB4() do{ \
  _Pragma("unroll") \
  for (int st_ = 0; st_ < 4; ++st_){ \
    half8 n0 = mk8(pk[0][st_], pk[1][st_]); \
    half8 n1 = mk8(pk[2][st_], pk[3][st_]); \
    half8 n2 = mk8(pk[4][st_], pk[5][st_]); \
    half8 n3 = mk8(pk[6][st_], pk[7][st_]); \
    bf[st_][0]=n0; bf[st_][1]=n1; bf[st_][2]=n2; bf[st_][3]=n3; \
  } \
}while(0)

__global__ __launch_bounds__(256, 2) void nerf_fused(
    const float* __restrict__ pos, const float* __restrict__ dirs,
    const _Float16* __restrict__ img,
    const float* __restrict__ b1, const float* __restrict__ b2,
    const float* __restrict__ b3, const float* __restrict__ b4,
    const float* __restrict__ bd, const float* __restrict__ bfl,
    const float* __restrict__ bc1, const float* __restrict__ bc2,
    float* __restrict__ out, int N) {
  __shared__ _Float16 wbuf[2][12288];   // 2 x 24 KB
  const int tid = threadIdx.x, wave = tid >> 6, lane = tid & 63;
  const int g = lane >> 4, n = lane & 15;
  const int pbase = blockIdx.x*256 + wave*64;

  half8 bf[4][5];
  uint2 pk[8][4];
  half8 dirf[4];

  STAGE(G1A, 0, 2);                    // chunk 1 staged during encode

  // ---- encode directly into B-fragment form ----
  const float PI = 3.14159265358979f;
  half8 z = {};
#pragma unroll
  for (int st = 0; st < 4; ++st) {
    int p = pbase + st*16 + n;
    float S[3][6], C[3][6];
    const float* pp = pos + (size_t)p*3;
#pragma unroll
    for (int d = 0; d < 3; ++d) {
      float x = pp[d]*PI;
      float s = __sinf(x), c = __cosf(x);
      S[d][0]=s; C[d][0]=c;
#pragma unroll
      for (int l = 1; l < 6; ++l) {
        float s2 = 2.f*s*c, c2 = c*c - s*s;
        S[d][l]=s2; C[d][l]=c2; s=s2; c=c2;
      }
    }
    half8 e0, e1 = z;
    if (g == 0) {
      e0 = mkh8(S[0][0],S[0][1],S[0][2],S[0][3],S[0][4],S[0][5],C[0][0],C[0][1]);
      e1 = mkh8(C[2][2],C[2][3],C[2][4],C[2][5],0.f,0.f,0.f,0.f);
    } else if (g == 1) {
      e0 = mkh8(C[0][2],C[0][3],C[0][4],C[0][5],S[1][0],S[1][1],S[1][2],S[1][3]);
    } else if (g == 2) {
      e0 = mkh8(S[1][4],S[1][5],C[1][0],C[1][1],C[1][2],C[1][3],C[1][4],C[1][5]);
    } else {
      e0 = mkh8(S[2][0],S[2][1],S[2][2],S[2][3],S[2][4],S[2][5],C[2][0],C[2][1]);
    }
    bf[st][0]=e0; bf[st][1]=e1;
    // dir encoding: lane g owns dir-dim g (g==3 -> zeros)
    float dv = (g < 3) ? dirs[(size_t)p*3 + g] : 0.f;
    float xx = dv*PI;
    float s1 = __sinf(xx), c1 = __cosf(xx);
    float sa[4], ca[4]; sa[0]=s1; ca[0]=c1;
#pragma unroll
    for (int l = 1; l < 4; ++l) {
      float s2 = 2.f*s1*c1, c2 = c1*c1 - s1*s1;
      sa[l]=s2; ca[l]=c2; s1=s2; c1=c2;
    }
    dirf[st] = (g < 3) ? mkh8(sa[0],sa[1],sa[2],sa[3],ca[0],ca[1],ca[2],ca[3]) : z;
  }
  __syncthreads();

  // ---- pipelined chunk sequence ----
  STAGE(G1B, 1, 2);  chunk64<128,2,0,true >(wbuf[0], lane, b1,     bf, pk); __syncthreads();
  STAGE(G2A, 0, 4);  chunk64<128,2,4,true >(wbuf[1], lane, b1+64,  bf, pk); __syncthreads();
  REB4();
  STAGE(G2B, 1, 4);  chunk64<256,4,0,true >(wbuf[0], lane, b2,     bf, pk); __syncthreads();
  STAGE(G3A, 0, 4);  chunk64<256,4,4,true >(wbuf[1], lane, b2+64,  bf, pk); __syncthreads();
  REB4();
  STAGE(G3B, 1, 4);  chunk64<256,4,0,true >(wbuf[0], lane, b3,     bf, pk); __syncthreads();
  STAGE(G4A, 0, 4);  chunk64<256,4,4,true >(wbuf[1], lane, b3+64,  bf, pk); __syncthreads();
  REB4();
  STAGE(G4B, 1, 4);  chunk64<256,4,0,true >(wbuf[0], lane, b4,     bf, pk); __syncthreads();
  STAGE(DCH, 0, 1);  chunk64<256,4,4,true >(wbuf[1], lane, b4+64,  bf, pk); __syncthreads();
  REB4();            // bf = geo_feat fragments (relu'd), shared by d, fa, fb
  STAGE(FAC, 1, 4);
  { // density head: [16][128], row dims 0..15 (dim0 real)
    const char* lb = (const char*)wbuf[0] + n*256;
    const int swz = (lane & 7) << 4;
    half8 wf[4];
#pragma unroll
    for (int ks = 0; ks < 4; ++ks)
      wf[ks] = *(const half8*)(lb + ((ks*64 + g*16) ^ swz));
    f32x4 a[4];
#pragma unroll
    for (int st = 0; st < 4; ++st) a[st] = f32x4{0.f,0.f,0.f,0.f};
#pragma unroll
    for (int ks = 0; ks < 4; ++ks)
#pragma unroll
      for (int st = 0; st < 4; ++st) a[st] = MFMA16(wf[ks], bf[st][ks], a[st]);
    if (g == 0) {
      float d0 = bd[0];
#pragma unroll
      for (int st = 0; st < 4; ++st) {
        float x = a[st][0] + d0;
        out[(size_t)3*N + pbase + st*16 + n] = fmaxf(x,0.f) + log1pf(__expf(-fabsf(x)));
      }
    }
  }
  __syncthreads();
  STAGE(FBC, 0, 4);  chunk64<256,4,0,false>(wbuf[1], lane, bfl,    bf, pk); __syncthreads();
  STAGE(C1C, 1, 6);  chunk64<256,4,4,false>(wbuf[0], lane, bfl+64, bf, pk); __syncthreads();
  REB4();            // bf = feature fragments
#pragma unroll
  for (int st = 0; st < 4; ++st) bf[st][4] = dirf[st];
  STAGE(C2C, 0, 1);  chunk64<384,5,0,true >(wbuf[1], lane, bc1,    bf, pk); __syncthreads();
  // rebuild c2 input (64 dims -> 2 ks) from c1's pk[0..3]
#pragma unroll
  for (int st = 0; st < 4; ++st) {
    half8 n0 = mk8(pk[0][st], pk[1][st]);
    half8 n1 = mk8(pk[2][st], pk[3][st]);
    bf[st][0]=n0; bf[st][1]=n1;
  }
  { // rgb head: [16][128] (k>=64 zero), rows 0..2 real
    const char* lb = (const char*)wbuf[0] + n*256;
    const int swz = (lane & 7) << 4;
    half8 wf[2];
#pragma unroll
    for (int ks = 0; ks < 2; ++ks)
      wf[ks] = *(const half8*)(lb + ((ks*64 + g*16) ^ swz));
    f32x4 a[4];
#pragma unroll
    for (int st = 0; st < 4; ++st) a[st] = f32x4{0.f,0.f,0.f,0.f};
#pragma unroll
    for (int ks = 0; ks < 2; ++ks)
#pragma unroll
      for (int st = 0; st < 4; ++st) a[st] = MFMA16(wf[ks], bf[st][ks], a[st]);
    if (g == 0) {
      float c0 = bc2[0], c1v = bc2[1], c2v = bc2[2];
#pragma unroll
      for (int st = 0; st < 4; ++st) {
        size_t p = (size_t)(pbase + st*16 + n);
        out[p*3+0] = 1.f/(1.f + __expf(-(a[st][0] + c0)));
        out[p*3+1] = 1.f/(1.f + __expf(-(a[st][1] + c1v)));
        out[p*3+2] = 1.f/(1.f + __expf(-(a[st][2] + c2v)));
      }
    }
  }
}

extern "C" void kernel_launch(void* const* d_in, const int* in_sizes, int n_in,
                              void* d_out, int out_size, void* d_ws, size_t ws_size,
                              hipStream_t stream) {
  const float* pos = (const float*)d_in[0];
  const float* dirs = (const float*)d_in[1];
  const float* g1w = (const float*)d_in[2];
  const float* g1b = (const float*)d_in[3];
  const float* g2w = (const float*)d_in[4];
  const float* g2b = (const float*)d_in[5];
  const float* g3w = (const float*)d_in[6];
  const float* g3b = (const float*)d_in[7];
  const float* g4w = (const float*)d_in[8];
  const float* g4b = (const float*)d_in[9];
  const float* dw  = (const float*)d_in[10];
  const float* db  = (const float*)d_in[11];
  const float* fw  = (const float*)d_in[12];
  const float* fb  = (const float*)d_in[13];
  const float* c1w = (const float*)d_in[14];
  const float* c1b = (const float*)d_in[15];
  const float* c2w = (const float*)d_in[16];
  const float* c2b = (const float*)d_in[17];

  int N = in_sizes[0] / 3;   // 1048576
  _Float16* img = (_Float16*)d_ws;

  prep<<<(IMG_HALVES + 255)/256, 256, 0, stream>>>(
      g1w, g2w, g3w, g4w, dw, fw, c1w, c2w, img);

  nerf_fused<<<N/256, 256, 0, stream>>>(
      pos, dirs, img, g1b, g2b, g3b, g4b, db, fb, c1b, c2b,
      (float*)d_out, N);
}